// Round 13
// baseline (82.758 us; speedup 1.0000x reference)
//
#include <hip/hip_runtime.h>

#define N_NODES 100000
#define BATCH   64
#define MID     32
#define TOTAL   (BATCH * N_NODES)
#define CHF     (N_NODES * 3)    // floats per channel per batch

typedef __attribute__((ext_vector_type(2))) __fp16 h2v;
typedef _Float16 __attribute__((ext_vector_type(8))) f16x8;
typedef float __attribute__((ext_vector_type(4))) f32x4;
typedef float __attribute__((ext_vector_type(2))) f32x2;

union H2U  { h2v h; unsigned int u; };
union U4H8 { uint4 u; f16x8 h; };

// align-4 vector wrappers: (...,3) f32 layout is only 4B-aligned
struct __attribute__((packed, aligned(4))) F4u { f32x4 v; };

// under-aligned vector typedefs for nontemporal stores
typedef f32x4 f32x4a4 __attribute__((aligned(4)));
typedef f32x2 f32x2a4 __attribute__((aligned(4)));
__device__ __forceinline__ void nts4(float* p, f32x4 v) { __builtin_nontemporal_store(v, (f32x4a4*)p); }
__device__ __forceinline__ void nts2(float* p, f32x2 v) { __builtin_nontemporal_store(v, (f32x2a4*)p); }
__device__ __forceinline__ void nts1(float* p, float v) { __builtin_nontemporal_store(v, p); }

// All three layers chained on MFMA via the jperm k-slot permutation:
// a relu-packed C (rows j on (q4,reg), cols pos) becomes the next B-operand with
// k = 8q4+m  ->  j = (m<4) ? 4q4+m : 16+4q4+(m-4)   [= jperm, verified R8]
// wf[0..127]  : W1^T A-frags, j-tiles 0/1 (k = channel 0..2, rest zero)
// wf[128..255]: W2^T A-frags, j-tiles 0/1, k-slots jperm'd
// wf[256..319]: W3^T A-frag (rows c>=3 zero), k-slots jperm'd
__global__ void prep_weights(const float* __restrict__ W1, const float* __restrict__ W2,
                             const float* __restrict__ W3, uint4* __restrict__ wf) {
    int t = threadIdx.x;   // 320 threads
    if (t >= 320) return;
    int l = t & 63;
    int q4 = l >> 4;
    if (t < 128) {
        int tile = t >> 6;
        int j = (l & 15) + 16 * tile;
        unsigned int pk0 = 0, pk1 = 0;
        if (q4 == 0) {
            H2U a; a.h = __builtin_amdgcn_cvt_pkrtz(W1[0 * MID + j], W1[1 * MID + j]);
            H2U b; b.h = __builtin_amdgcn_cvt_pkrtz(W1[2 * MID + j], 0.f);
            pk0 = a.u; pk1 = b.u;
        }
        wf[t] = make_uint4(pk0, pk1, 0u, 0u);
    } else if (t < 256) {
        int tt = t - 128;
        int tile = tt >> 6;
        int j2 = (l & 15) + 16 * tile;
        unsigned int pk[4];
#pragma unroll
        for (int mp = 0; mp < 4; ++mp) {
            int jb = (mp < 2) ? (4*q4 + 2*mp) : (16 + 4*q4 + 2*(mp - 2));
            H2U a; a.h = __builtin_amdgcn_cvt_pkrtz(W2[jb * MID + j2], W2[(jb + 1) * MID + j2]);
            pk[mp] = a.u;
        }
        wf[128 + tt] = make_uint4(pk[0], pk[1], pk[2], pk[3]);
    } else {
        int c = l & 15;
        unsigned int pk[4];
#pragma unroll
        for (int mp = 0; mp < 4; ++mp) {
            int jb = (mp < 2) ? (4*q4 + 2*mp) : (16 + 4*q4 + 2*(mp - 2));
            float x0 = (c < 3) ? W3[jb * 6 + c] : 0.f;
            float x1 = (c < 3) ? W3[(jb + 1) * 6 + c] : 0.f;
            H2U a; a.h = __builtin_amdgcn_cvt_pkrtz(x0, x1);
            pk[mp] = a.u;
        }
        wf[256 + l] = make_uint4(pk[0], pk[1], pk[2], pk[3]);
    }
}

// Softmax is degenerate (dst bijection -> alpha == 1 exactly); q/Wq/key unused.
// R12 structure (NT stores) with layer-1 moved onto MFMA: the h1 LDS round-trip
// (4 b128 writes + 4 b128 reads per wave) is replaced by 8 b32 shuffles of the
// p-side edge pack; L1->L2->L3 chain lives entirely in registers (jperm frags).
// LDS = 512 B/wave z-buffer only. Wave-private, in-order DS pipe -> no barriers.
__global__ __launch_bounds__(256) void xattn_kernel(
    const float* __restrict__ in,
    const float* __restrict__ b1,
    const float* __restrict__ b2,
    const uint4* __restrict__ wf,
    const float* __restrict__ Wp,
    float* __restrict__ out)
{
    __shared__ __attribute__((aligned(16))) char ldsbuf[4 * 512];   // 2048 B: z-buffers
    int tid  = threadIdx.x;
    int lane = tid & 63;
    int wave = tid >> 6;
    char* ZB = ldsbuf + wave * 512;         // [64][8B] z per position

    int idx = blockIdx.x * 256 + tid;       // grid covers exactly B*N
    int b = idx / N_NODES;
    int n = idx - b * N_NODES;
    bool last  = (idx == TOTAL - 1);        // 4B-OOB exposure on the edge LOAD
    bool btail = (n == N_NODES - 1);        // ch2 overlap STORE would hit next batch's out0

    const float* inb  = in  + (size_t)b * 3 * CHF;
    float*       outb = out + (size_t)b * 3 * CHF;

    // ---- overlap-vec4 loads: node[n], ch1[n], edge[n] ----
    f32x4 ndv = ((const F4u*)(inb + (size_t)n * 3))->v;
    f32x4 c1v = ((const F4u*)(inb + (size_t)CHF + (size_t)n * 3))->v;
    f32x4 edv;
    const float* e_ptr = inb + (size_t)2 * CHF + (size_t)n * 3;
    if (!last) edv = ((const F4u*)e_ptr)->v;
    else       edv = (f32x4){e_ptr[0], e_ptr[1], e_ptr[2], 0.f};

    float qn0 = ndv.x, qn1 = ndv.y, qn2 = ndv.z;

    // ---- pass-through stores (ch1, ch2), NON-TEMPORAL ----
    {
        float* o1p = outb + (size_t)CHF + (size_t)n * 3;
        nts4(o1p, c1v);                    // 4th dword: benign (same value as neighbor's)
        float* o2p = outb + (size_t)2 * CHF + (size_t)n * 3;
        if (!btail) nts4(o2p, edv);        // 4th dword benign within batch
        else { nts1(o2p, edv.x); nts1(o2p + 1, edv.y); nts1(o2p + 2, edv.z); }
    }

    // ---- p-side via f16-packed shuffle (3 bpermutes); boundary lanes load ----
    H2U s0_, s1_, s2_;
    s0_.h = __builtin_amdgcn_cvt_pkrtz(qn0, qn1);     // (n0, n1)
    s1_.h = __builtin_amdgcn_cvt_pkrtz(qn2, edv.x);   // (n2, e0)
    s2_.h = __builtin_amdgcn_cvt_pkrtz(edv.y, edv.z); // (e1, e2)
    unsigned int t0 = __shfl_up(s0_.u, 1);
    unsigned int t1 = __shfl_up(s1_.u, 1);
    unsigned int t2 = __shfl_up(s2_.u, 1);
    if (lane == 0 || n == 0) {
        int p = (n == 0) ? (N_NODES - 1) : (n - 1);
        const float* np_ = inb + (size_t)p * 3;
        const float* epp = inb + (size_t)2 * CHF + (size_t)p * 3;
        H2U a, bb, c;
        a.h  = __builtin_amdgcn_cvt_pkrtz(np_[0], np_[1]);
        bb.h = __builtin_amdgcn_cvt_pkrtz(np_[2], epp[0]);
        c.h  = __builtin_amdgcn_cvt_pkrtz(epp[1], epp[2]);
        t0 = a.u; t1 = bb.u; t2 = c.u;
    }
    H2U u0, u1, u2; u0.u = t0; u1.u = t1; u2.u = t2;
    float pp0 = (float)u0.h[0], pp1 = (float)u0.h[1], pp2 = (float)u1.h[0];
    // edge[p] of THIS lane's position, packed as f16 pairs (e0,e1) and (e2,0)
    unsigned int epk0 = __builtin_amdgcn_alignbit(u2.u, u1.u, 16);  // lo=e0, hi=e1
    unsigned int epk1 = u2.u >> 16;                                 // lo=e2, hi=0

    // ---- per-lane constant frags ----
    int r16 = lane & 15;   // C-col = position within tile / B-col
    int q4  = lane >> 4;   // k-group / C-row-group
    U4H8 w1a0; w1a0.u = wf[lane];
    U4H8 w1a1; w1a1.u = wf[64 + lane];
    U4H8 w2a0; w2a0.u = wf[128 + lane];
    U4H8 w2a1; w2a1.u = wf[192 + lane];
    U4H8 w3a;  w3a.u  = wf[256 + lane];
    f32x4 b1i0 = *(const f32x4*)(b1 + 4*q4);       // C rows j = 4q4 + r
    f32x4 b1i1 = *(const f32x4*)(b1 + 16 + 4*q4);
    f32x4 b2i0 = *(const f32x4*)(b2 + 4*q4);
    f32x4 b2i1 = *(const f32x4*)(b2 + 16 + 4*q4);
    h2v zz = {(__fp16)0.0f, (__fp16)0.0f};

    // ---- per pos-tile: MFMA L1 -> pack -> MFMA L2 -> pack -> MFMA L3 -> z ----
#pragma unroll
    for (int pt = 0; pt < 4; ++pt) {
        // B1: edge[p] of position pt*16+r16, on k=0..2 of q4==0 lanes only
        unsigned int e0f = __shfl(epk0, pt*16 + r16);
        unsigned int e1f = __shfl(epk1, pt*16 + r16);
        U4H8 b1f; b1f.u = make_uint4(q4 == 0 ? e0f : 0u, q4 == 0 ? e1f : 0u, 0u, 0u);

        f32x4 a0 = b1i0, a1 = b1i1;
        a0 = __builtin_amdgcn_mfma_f32_16x16x32_f16(w1a0.h, b1f.h, a0, 0, 0, 0);
        a1 = __builtin_amdgcn_mfma_f32_16x16x32_f16(w1a1.h, b1f.h, a1, 0, 0, 0);

        // relu+pack h1 -> B2 frag (jperm layout; W2^T frags pre-permuted to match)
        H2U g0, g1, g2, g3;
        g0.h = __builtin_elementwise_max(__builtin_amdgcn_cvt_pkrtz(a0[0], a0[1]), zz);
        g1.h = __builtin_elementwise_max(__builtin_amdgcn_cvt_pkrtz(a0[2], a0[3]), zz);
        g2.h = __builtin_elementwise_max(__builtin_amdgcn_cvt_pkrtz(a1[0], a1[1]), zz);
        g3.h = __builtin_elementwise_max(__builtin_amdgcn_cvt_pkrtz(a1[2], a1[3]), zz);
        U4H8 b2f; b2f.u = make_uint4(g0.u, g1.u, g2.u, g3.u);

        f32x4 c0 = b2i0, c1 = b2i1;
        c0 = __builtin_amdgcn_mfma_f32_16x16x32_f16(w2a0.h, b2f.h, c0, 0, 0, 0);
        c1 = __builtin_amdgcn_mfma_f32_16x16x32_f16(w2a1.h, b2f.h, c1, 0, 0, 0);

        // relu+pack h2 -> B3 frag
        H2U k0, k1, k2, k3;
        k0.h = __builtin_elementwise_max(__builtin_amdgcn_cvt_pkrtz(c0[0], c0[1]), zz);
        k1.h = __builtin_elementwise_max(__builtin_amdgcn_cvt_pkrtz(c0[2], c0[3]), zz);
        k2.h = __builtin_elementwise_max(__builtin_amdgcn_cvt_pkrtz(c1[0], c1[1]), zz);
        k3.h = __builtin_elementwise_max(__builtin_amdgcn_cvt_pkrtz(c1[2], c1[3]), zz);
        U4H8 b3f; b3f.u = make_uint4(k0.u, k1.u, k2.u, k3.u);

        f32x4 c3 = __builtin_amdgcn_mfma_f32_16x16x32_f16(w3a.h, b3f.h,
                                                          (f32x4){0.f,0.f,0.f,0.f}, 0, 0, 0);

        // rows c = 4q4 + r -> q4==0 lanes hold c=0..2 for position pt*16 + r16
        if (q4 == 0) {
            H2U za; za.h = __builtin_amdgcn_cvt_pkrtz(c3[0], c3[1]);
            H2U zb; zb.h = __builtin_amdgcn_cvt_pkrtz(c3[2], 0.f);
            *(uint2*)(ZB + (pt*16 + r16) * 8) = make_uint2(za.u, zb.u);
        }
    }

    // ---- tail: z = r . node[p]; out0 = Wp . [z, node[n]] (NON-TEMPORAL) ----
    uint2 zr = *(const uint2*)(ZB + lane * 8);
    H2U za, zb; za.u = zr.x; zb.u = zr.y;
    float z = fmaf((float)za.h[0], pp0,
              fmaf((float)za.h[1], pp1, (float)zb.h[0] * pp2));

    float vo[3];
#pragma unroll
    for (int o = 0; o < 3; ++o) {
        float v = Wp[o*4 + 0] * z;
        v = fmaf(Wp[o*4 + 1], qn0, v);
        v = fmaf(Wp[o*4 + 2], qn1, v);
        v = fmaf(Wp[o*4 + 3], qn2, v);
        vo[o] = v;
    }
    float* o0 = outb + (size_t)n * 3;
    nts2(o0, (f32x2){vo[0], vo[1]});
    nts1(o0 + 2, vo[2]);
}

extern "C" void kernel_launch(void* const* d_in, const int* in_sizes, int n_in,
                              void* d_out, int out_size, void* d_ws, size_t ws_size,
                              hipStream_t stream) {
    const float* in = (const float*)d_in[0];
    const float* W1 = (const float*)d_in[1];
    const float* b1 = (const float*)d_in[2];
    const float* W2 = (const float*)d_in[3];
    const float* b2 = (const float*)d_in[4];
    const float* W3 = (const float*)d_in[5];
    // d_in[6] = Wq — provably unused (softmax weights are exactly 1)
    const float* Wp = (const float*)d_in[7];
    float* out = (float*)d_out;

    uint4* wf = (uint4*)d_ws;   // 320 * 16 B = 5120 B scratch
    hipLaunchKernelGGL(prep_weights, dim3(1), dim3(320), 0, stream, W1, W2, W3, wf);

    int blocks = TOTAL / 256;   // 25000, exact
    hipLaunchKernelGGL(xattn_kernel, dim3(blocks), dim3(256), 0, stream,
                       in, b1, b2, wf, Wp, out);
}

// Round 14
// 79.597 us; speedup vs baseline: 1.0397x; 1.0397x over previous
//
#include <hip/hip_runtime.h>

#define N_NODES 100000
#define BATCH   64
#define MID     32
#define LSTRIDE 80               // h1 row stride (bytes); bytes [64,80) of each row = ZB overlay
#define WLDS    (64 * LSTRIDE)   // per-wave LDS: 5120 B -> 4 waves = 20480 B = 8 blocks/CU
#define TOTAL   (BATCH * N_NODES)
#define CHF     (N_NODES * 3)    // floats per channel per batch

typedef __attribute__((ext_vector_type(2))) __fp16 h2v;
typedef _Float16 __attribute__((ext_vector_type(8))) f16x8;
typedef float __attribute__((ext_vector_type(4))) f32x4;
typedef float __attribute__((ext_vector_type(2))) f32x2;

union H2U  { h2v h; unsigned int u; };
union U4H8 { uint4 u; f16x8 h; };

// align-4 vector wrappers: (...,3) f32 layout is only 4B-aligned
struct __attribute__((packed, aligned(4))) F4u { f32x4 v; };

// under-aligned vector typedefs for nontemporal stores
typedef f32x4 f32x4a4 __attribute__((aligned(4)));
typedef f32x2 f32x2a4 __attribute__((aligned(4)));
__device__ __forceinline__ void nts4(float* p, f32x4 v) { __builtin_nontemporal_store(v, (f32x4a4*)p); }
__device__ __forceinline__ void nts2(float* p, f32x2 v) { __builtin_nontemporal_store(v, (f32x2a4*)p); }
__device__ __forceinline__ void nts1(float* p, float v) { __builtin_nontemporal_store(v, p); }

// wf[0..63]   : W2^T A-frag, j-tile 0   (row j = lane&15, k-slot (lane>>4)*8+m = cin)
// wf[64..127] : W2^T A-frag, j-tile 1
// wf[128..191]: W3^T A-frag (row c = lane&15, k-slot (q4,m) -> j = m<4 ? 4q4+m : 16+4q4+m-4;
//               rows c>=3 zero) — matches the k-perm of the acc-register B-operand.
// aux[0..47]  : W1 packed f16 pairs; aux[48..63]: b1 packed f16 pairs
__global__ void prep_weights(const float* __restrict__ W1, const float* __restrict__ b1,
                             const float* __restrict__ W2, const float* __restrict__ W3,
                             uint4* __restrict__ wf, unsigned int* __restrict__ aux) {
    int t = threadIdx.x;
    if (t < 128) {
        int grp = t >> 6, l = t & 63;
        int j = (l & 15) + 16 * grp, k0 = (l >> 4) * 8;
        unsigned int pk[4];
#pragma unroll
        for (int m = 0; m < 4; ++m) {
            H2U a; a.h = __builtin_amdgcn_cvt_pkrtz(W2[(k0 + 2*m) * MID + j],
                                                    W2[(k0 + 2*m + 1) * MID + j]);
            pk[m] = a.u;
        }
        wf[t] = make_uint4(pk[0], pk[1], pk[2], pk[3]);
    } else if (t < 192) {
        int l = t & 63;
        int c = l & 15, q4 = l >> 4;
        unsigned int pk[4];
#pragma unroll
        for (int mp = 0; mp < 4; ++mp) {
            int jb = (mp < 2) ? (4*q4 + 2*mp) : (16 + 4*q4 + 2*(mp - 2));
            float x0 = (c < 3) ? W3[jb * 6 + c] : 0.f;
            float x1 = (c < 3) ? W3[(jb + 1) * 6 + c] : 0.f;
            H2U a; a.h = __builtin_amdgcn_cvt_pkrtz(x0, x1);
            pk[mp] = a.u;
        }
        wf[128 + l] = make_uint4(pk[0], pk[1], pk[2], pk[3]);
    } else if (t < 240) {
        int i = t - 192;
        int k = i >> 4, m = i & 15;
        H2U a; a.h = __builtin_amdgcn_cvt_pkrtz(W1[k * MID + 2*m], W1[k * MID + 2*m + 1]);
        aux[i] = a.u;
    } else {
        int m = t - 240;
        H2U a; a.h = __builtin_amdgcn_cvt_pkrtz(b1[2*m], b1[2*m + 1]);
        aux[48 + m] = a.u;
    }
}

// Softmax is degenerate (dst bijection -> alpha == 1 exactly); q/Wq/key unused.
// R12 body verbatim, 2-DEEP SOFTWARE PIPELINE: each block owns 512 positions;
// BOTH groups' global loads issue up front (6 vec4 in flight), then the full R12
// body runs per group. vmcnt FIFO => g0 compute waits only on g0's (older) loads,
// g1's stay in flight underneath. LDS reuse across groups is safe (per-wave
// in-order DS pipe). NT stores throughout (the R12 win).
__global__ __launch_bounds__(256) void xattn_kernel(
    const float* __restrict__ in,
    const unsigned int* __restrict__ aux,   // w1p / b1p
    const float* __restrict__ b2,
    const uint4* __restrict__ wf,
    const float* __restrict__ Wp,
    float* __restrict__ out)
{
    __shared__ __attribute__((aligned(16))) char ldsbuf[4 * WLDS];   // 20480 B
    int tid  = threadIdx.x;
    int lane = tid & 63;
    int wave = tid >> 6;
    char* L  = ldsbuf + wave * WLDS;        // h1 rows [64][LSTRIDE]; pad bytes 64..79 = ZB

    // ---- phase 0: issue ALL loads for both groups ----
    f32x4 ndv[2], c1v[2], edv[2];
    int npos[2], bb[2];
#pragma unroll
    for (int g = 0; g < 2; ++g) {
        int idx = blockIdx.x * 512 + g * 256 + tid;   // grid*512 covers exactly B*N
        int b = idx / N_NODES;
        int n = idx - b * N_NODES;
        bb[g] = b; npos[g] = n;
        const float* inb = in + (size_t)b * 3 * CHF;
        ndv[g] = ((const F4u*)(inb + (size_t)n * 3))->v;
        c1v[g] = ((const F4u*)(inb + (size_t)CHF + (size_t)n * 3))->v;
        const float* e_ptr = inb + (size_t)2 * CHF + (size_t)n * 3;
        if (idx != TOTAL - 1) edv[g] = ((const F4u*)e_ptr)->v;
        else                  edv[g] = (f32x4){e_ptr[0], e_ptr[1], e_ptr[2], 0.f};
    }

    // ---- per-lane constants (shared by both groups) ----
    int r16 = lane & 15;   // C-col = position within tile / B-col
    int q4  = lane >> 4;   // k-group / C-row-group
    U4H8 wb20; wb20.u = wf[lane];
    U4H8 wb21; wb21.u = wf[64 + lane];
    U4H8 wb3;  wb3.u  = wf[128 + lane];
    f32x4 bi0 = *(const f32x4*)(b2 + 4*q4);        // b2[j], j = 4q4 + r  (C-rows)
    f32x4 bi1 = *(const f32x4*)(b2 + 16 + 4*q4);
    h2v zz = {(__fp16)0.0f, (__fp16)0.0f};

    // ---- phase 1/2: full R12 body per group ----
#pragma unroll
    for (int g = 0; g < 2; ++g) {
        int b = bb[g], n = npos[g];
        int idx = b * N_NODES + n;
        bool btail = (n == N_NODES - 1);
        const float* inb  = in  + (size_t)b * 3 * CHF;
        float*       outb = out + (size_t)b * 3 * CHF;

        float qn0 = ndv[g].x, qn1 = ndv[g].y, qn2 = ndv[g].z;

        // pass-through stores (ch1, ch2), NON-TEMPORAL
        {
            float* o1p = outb + (size_t)CHF + (size_t)n * 3;
            nts4(o1p, c1v[g]);                 // 4th dword: benign (same value as neighbor's)
            float* o2p = outb + (size_t)2 * CHF + (size_t)n * 3;
            if (!btail) nts4(o2p, edv[g]);     // 4th dword benign within batch
            else { nts1(o2p, edv[g].x); nts1(o2p + 1, edv[g].y); nts1(o2p + 2, edv[g].z); }
        }

        // p-side via f16-packed shuffle (3 bpermutes); boundary lanes load
        H2U s0_, s1_, s2_;
        s0_.h = __builtin_amdgcn_cvt_pkrtz(qn0, qn1);           // (n0, n1)
        s1_.h = __builtin_amdgcn_cvt_pkrtz(qn2, edv[g].x);      // (n2, e0)
        s2_.h = __builtin_amdgcn_cvt_pkrtz(edv[g].y, edv[g].z); // (e1, e2)
        unsigned int t0 = __shfl_up(s0_.u, 1);
        unsigned int t1 = __shfl_up(s1_.u, 1);
        unsigned int t2 = __shfl_up(s2_.u, 1);
        if (lane == 0 || n == 0) {
            int p = (n == 0) ? (N_NODES - 1) : (n - 1);
            const float* np_ = inb + (size_t)p * 3;
            const float* epp = inb + (size_t)2 * CHF + (size_t)p * 3;
            H2U a, bbp, c;
            a.h   = __builtin_amdgcn_cvt_pkrtz(np_[0], np_[1]);
            bbp.h = __builtin_amdgcn_cvt_pkrtz(np_[2], epp[0]);
            c.h   = __builtin_amdgcn_cvt_pkrtz(epp[1], epp[2]);
            t0 = a.u; t1 = bbp.u; t2 = c.u;
        }
        H2U u0, u1, u2; u0.u = t0; u1.u = t1; u2.u = t2;
        float pp0 = (float)u0.h[0], pp1 = (float)u0.h[1], pp2 = (float)u1.h[0];
        h2v eh0 = {u1.h[1], u1.h[1]};
        h2v eh1 = {u2.h[0], u2.h[0]};
        h2v eh2 = {u2.h[1], u2.h[1]};

        // layer 1: packed f16 (v_pk_fma_f16), relu -> LDS rows [pos][32 f16]
        unsigned int hp[16];
#pragma unroll
        for (int m = 0; m < 16; ++m) {
            H2U acc, w0, w1_, w2_;
            acc.u = aux[48 + m];
            w0.u  = aux[m];
            w1_.u = aux[16 + m];
            w2_.u = aux[32 + m];
            acc.h = eh0 * w0.h + acc.h;
            acc.h = eh1 * w1_.h + acc.h;
            acc.h = eh2 * w2_.h + acc.h;
            acc.h = __builtin_elementwise_max(acc.h, zz);
            hp[m] = acc.u;
        }
        {
            uint4* row = (uint4*)(L + lane * LSTRIDE);
            row[0] = make_uint4(hp[0],  hp[1],  hp[2],  hp[3]);
            row[1] = make_uint4(hp[4],  hp[5],  hp[6],  hp[7]);
            row[2] = make_uint4(hp[8],  hp[9],  hp[10], hp[11]);
            row[3] = make_uint4(hp[12], hp[13], hp[14], hp[15]);
        }

        // per pos-tile: swapped MFMA2 -> reg-pack -> swapped MFMA3 -> z-write
#pragma unroll
        for (int pt = 0; pt < 4; ++pt) {
            U4H8 hB; hB.u = *(const uint4*)(L + (pt*16 + r16) * LSTRIDE + q4 * 16);
            f32x4 acc0 = bi0;
            f32x4 acc1 = bi1;
            acc0 = __builtin_amdgcn_mfma_f32_16x16x32_f16(wb20.h, hB.h, acc0, 0, 0, 0);
            acc1 = __builtin_amdgcn_mfma_f32_16x16x32_f16(wb21.h, hB.h, acc1, 0, 0, 0);

            H2U g0, g1, g2, g3;
            g0.h = __builtin_elementwise_max(__builtin_amdgcn_cvt_pkrtz(acc0[0], acc0[1]), zz);
            g1.h = __builtin_elementwise_max(__builtin_amdgcn_cvt_pkrtz(acc0[2], acc0[3]), zz);
            g2.h = __builtin_elementwise_max(__builtin_amdgcn_cvt_pkrtz(acc1[0], acc1[1]), zz);
            g3.h = __builtin_elementwise_max(__builtin_amdgcn_cvt_pkrtz(acc1[2], acc1[3]), zz);
            U4H8 b3f; b3f.u = make_uint4(g0.u, g1.u, g2.u, g3.u);

            f32x4 c3 = __builtin_amdgcn_mfma_f32_16x16x32_f16(wb3.h, b3f.h,
                                                              (f32x4){0.f,0.f,0.f,0.f}, 0, 0, 0);

            // rows c = 4q4 + r -> q4==0 lanes hold c=0..2 for position pos = pt*16 + r16.
            // ZB overlay: z of position pos lives in row pos>>1's pad, byte 64 + (pos&1)*8.
            if (q4 == 0) {
                int pos = pt*16 + r16;
                H2U za; za.h = __builtin_amdgcn_cvt_pkrtz(c3[0], c3[1]);
                H2U zb; zb.h = __builtin_amdgcn_cvt_pkrtz(c3[2], 0.f);
                *(uint2*)(L + (pos >> 1) * LSTRIDE + 64 + (pos & 1) * 8) = make_uint2(za.u, zb.u);
            }
        }

        // tail: z = r . node[p]; out0 = Wp . [z, node[n]] (NON-TEMPORAL)
        uint2 zr = *(const uint2*)(L + (lane >> 1) * LSTRIDE + 64 + (lane & 1) * 8);
        H2U za, zb; za.u = zr.x; zb.u = zr.y;
        float z = fmaf((float)za.h[0], pp0,
                  fmaf((float)za.h[1], pp1, (float)zb.h[0] * pp2));

        float vo[3];
#pragma unroll
        for (int o = 0; o < 3; ++o) {
            float v = Wp[o*4 + 0] * z;
            v = fmaf(Wp[o*4 + 1], qn0, v);
            v = fmaf(Wp[o*4 + 2], qn1, v);
            v = fmaf(Wp[o*4 + 3], qn2, v);
            vo[o] = v;
        }
        float* o0 = outb + (size_t)n * 3;
        nts2(o0, (f32x2){vo[0], vo[1]});
        nts1(o0 + 2, vo[2]);
        (void)idx;
    }
}

extern "C" void kernel_launch(void* const* d_in, const int* in_sizes, int n_in,
                              void* d_out, int out_size, void* d_ws, size_t ws_size,
                              hipStream_t stream) {
    const float* in = (const float*)d_in[0];
    const float* W1 = (const float*)d_in[1];
    const float* b1 = (const float*)d_in[2];
    const float* W2 = (const float*)d_in[3];
    const float* b2 = (const float*)d_in[4];
    const float* W3 = (const float*)d_in[5];
    // d_in[6] = Wq — provably unused (softmax weights are exactly 1)
    const float* Wp = (const float*)d_in[7];
    float* out = (float*)d_out;

    uint4* wf = (uint4*)d_ws;                        // 192 * 16 B
    unsigned int* aux = (unsigned int*)(wf + 192);   // 64 * 4 B
    hipLaunchKernelGGL(prep_weights, dim3(1), dim3(256), 0, stream, W1, b1, W2, W3, wf, aux);

    int blocks = TOTAL / 512;   // 12500, exact
    hipLaunchKernelGGL(xattn_kernel, dim3(blocks), dim3(256), 0, stream,
                       in, aux, b2, wf, Wp, out);
}